// Round 3
// baseline (2075.284 us; speedup 1.0000x reference)
//
#include <hip/hip_runtime.h>
#include <hip/hip_bf16.h>

#define N_NODES 100000
#define N_EDGES 1600000

// ---------------------------------------------------------------------------
// GEMM: out[N, DOUT] = (RELU? max(H,0):H)[N, DIN] @ W[DIN, DOUT] + b[DOUT]
// One thread per output element; W staged in LDS (max 128*64*4 = 32 KB).
// ---------------------------------------------------------------------------
template <int DIN, int DOUT, bool RELU>
__global__ void gemm_bias(const float* __restrict__ H, const float* __restrict__ W,
                          const float* __restrict__ b, float* __restrict__ out, int N) {
    __shared__ float Ws[DIN * DOUT];
    for (int i = threadIdx.x; i < DIN * DOUT; i += blockDim.x) Ws[i] = W[i];
    __syncthreads();

    int gid = blockIdx.x * blockDim.x + threadIdx.x;
    int row = gid / DOUT;
    int col = gid - row * DOUT;
    if (row >= N) return;

    const float* h = H + (long)row * DIN;
    float acc = b[col];
#pragma unroll
    for (int k = 0; k < DIN; ++k) {
        float x = h[k];
        if (RELU) x = fmaxf(x, 0.0f);
        acc = fmaf(x, Ws[k * DOUT + col], acc);
    }
    out[gid] = acc;
}

// ---------------------------------------------------------------------------
// Scatter for dout=64: one wave per edge, lane = feature.
// out[dst[e]][f] += H[src[e]][f] * w[e]   (atomic, fp32)
// ---------------------------------------------------------------------------
__global__ void scatter64(const float* __restrict__ H, const int* __restrict__ src,
                          const int* __restrict__ dst, const float* __restrict__ w,
                          float* __restrict__ out, int E) {
    int lane = threadIdx.x & 63;
    long wid = ((long)blockIdx.x * blockDim.x + threadIdx.x) >> 6;
    long nw  = ((long)gridDim.x * blockDim.x) >> 6;
    for (long e = wid; e < E; e += nw) {
        int s = src[e];
        int d = dst[e];
        float we = w[e];
        float v = H[(long)s * 64 + lane] * we;
        atomicAdd(&out[(long)d * 64 + lane], v);
    }
}

// ---------------------------------------------------------------------------
// Scatter for dout=10 (final layer): thread per (edge, feature), packed.
// ---------------------------------------------------------------------------
__global__ void scatter10(const float* __restrict__ H, const int* __restrict__ src,
                          const int* __restrict__ dst, const float* __restrict__ w,
                          float* __restrict__ out, int E) {
    int gid = blockIdx.x * blockDim.x + threadIdx.x;
    int total = E * 10;
    int stride = gridDim.x * blockDim.x;
    for (int i = gid; i < total; i += stride) {
        int e = i / 10;
        int f = i - e * 10;
        int s = src[e];
        int d = dst[e];
        float v = H[(long)s * 10 + f] * w[e];
        atomicAdd(&out[(long)d * 10 + f], v);
    }
}

extern "C" void kernel_launch(void* const* d_in, const int* in_sizes, int n_in,
                              void* d_out, int out_size, void* d_ws, size_t ws_size,
                              hipStream_t stream) {
    const float* x        = (const float*)d_in[0];
    const int*   edge_src = (const int*)d_in[1];
    const int*   edge_dst = (const int*)d_in[2];
    const float* edge_w   = (const float*)d_in[3];
    const float* W0 = (const float*)d_in[4];
    const float* b0 = (const float*)d_in[5];
    const float* W1 = (const float*)d_in[6];
    const float* b1 = (const float*)d_in[7];
    const float* W2 = (const float*)d_in[8];
    const float* b2 = (const float*)d_in[9];
    const float* W3 = (const float*)d_in[10];
    const float* b3 = (const float*)d_in[11];
    const float* W4 = (const float*)d_in[12];
    const float* b4 = (const float*)d_in[13];
    float* out = (float*)d_out;

    // Workspace layout: P (projected) | A (aggregated), each 100000*64 floats.
    const size_t BUF = (size_t)N_NODES * 64 * sizeof(float);  // 25.6 MB
    float* P = (float*)d_ws;
    float* A = (float*)((char*)d_ws + BUF);

    const int GEMM_BLK = 256;
    const int SC_BLOCKS = 2048;  // 8192 waves = full occupancy

    // ---- Layer 0: x[100000,128] @ W0 -> P ; scatter -> A ----
    {
        int total = N_NODES * 64;
        gemm_bias<128, 64, false><<<(total + GEMM_BLK - 1) / GEMM_BLK, GEMM_BLK, 0, stream>>>(
            x, W0, b0, P, N_NODES);
        hipMemsetAsync(A, 0, BUF, stream);
        scatter64<<<SC_BLOCKS, 256, 0, stream>>>(P, edge_src, edge_dst, edge_w, A, N_EDGES);
    }

    // ---- Layers 1..3: relu(A) @ W -> P ; scatter -> A ----
    const float* Ws_[3] = {W1, W2, W3};
    const float* bs_[3] = {b1, b2, b3};
    for (int l = 0; l < 3; ++l) {
        int total = N_NODES * 64;
        gemm_bias<64, 64, true><<<(total + GEMM_BLK - 1) / GEMM_BLK, GEMM_BLK, 0, stream>>>(
            A, Ws_[l], bs_[l], P, N_NODES);
        hipMemsetAsync(A, 0, BUF, stream);
        scatter64<<<SC_BLOCKS, 256, 0, stream>>>(P, edge_src, edge_dst, edge_w, A, N_EDGES);
    }

    // ---- Layer 4: relu(A) @ W4 -> P10 ; scatter10 -> out ----
    {
        int total = N_NODES * 10;
        gemm_bias<64, 10, true><<<(total + GEMM_BLK - 1) / GEMM_BLK, GEMM_BLK, 0, stream>>>(
            A, W4, b4, P, N_NODES);
        hipMemsetAsync(out, 0, (size_t)N_NODES * 10 * sizeof(float), stream);
        scatter10<<<SC_BLOCKS, 256, 0, stream>>>(P, edge_src, edge_dst, edge_w, out, N_EDGES);
    }
}

// Round 5
// 914.422 us; speedup vs baseline: 2.2695x; 2.2695x over previous
//
#include <hip/hip_runtime.h>
#include <hip/hip_bf16.h>

#define N_NODES 100000
#define N_EDGES 1600000

// ============================ CSR build ====================================
__global__ void hist_kernel(const int* __restrict__ dst, int* __restrict__ deg, int E) {
    int gid = blockIdx.x * blockDim.x + threadIdx.x;
    if (gid < E) atomicAdd(&deg[dst[gid]], 1);
}

// chunked exclusive scan, 1024-wide blocks
__global__ void scan1(const int* __restrict__ deg, int* __restrict__ row_ptr,
                      int* __restrict__ partials, int N) {
    __shared__ int sh[1024];
    int gid = blockIdx.x * 1024 + threadIdx.x;
    int v = (gid < N) ? deg[gid] : 0;
    sh[threadIdx.x] = v;
    __syncthreads();
    for (int off = 1; off < 1024; off <<= 1) {
        int t = (threadIdx.x >= off) ? sh[threadIdx.x - off] : 0;
        __syncthreads();
        sh[threadIdx.x] += t;
        __syncthreads();
    }
    if (gid < N) row_ptr[gid] = sh[threadIdx.x] - v;  // exclusive
    if (threadIdx.x == 1023) partials[blockIdx.x] = sh[1023];
}

__global__ void scan2(int* __restrict__ partials, int nb) {
    __shared__ int sh[128];
    int v = (threadIdx.x < nb) ? partials[threadIdx.x] : 0;
    sh[threadIdx.x] = v;
    __syncthreads();
    for (int off = 1; off < 128; off <<= 1) {
        int t = (threadIdx.x >= off) ? sh[threadIdx.x - off] : 0;
        __syncthreads();
        sh[threadIdx.x] += t;
        __syncthreads();
    }
    if (threadIdx.x < nb) partials[threadIdx.x] = sh[threadIdx.x] - v;
}

__global__ void scan3(int* __restrict__ row_ptr, int* __restrict__ cursor,
                      const int* __restrict__ partials, int N, int E) {
    int gid = blockIdx.x * 1024 + threadIdx.x;
    if (gid < N) {
        int r = row_ptr[gid] + partials[blockIdx.x];
        row_ptr[gid] = r;
        cursor[gid] = r;
    }
    if (gid == 0) row_ptr[N] = E;
}

__global__ void place_kernel(const int* __restrict__ src, const int* __restrict__ dst,
                             const float* __restrict__ w, int* __restrict__ cursor,
                             int* __restrict__ csr_src, float* __restrict__ csr_w, int E) {
    int gid = blockIdx.x * blockDim.x + threadIdx.x;
    if (gid < E) {
        int d = dst[gid];
        int pos = atomicAdd(&cursor[d], 1);
        csr_src[pos] = src[gid];
        csr_w[pos]   = w[gid];
    }
}

// ============================ GEMM =========================================
// out[N,DOUT] = relu?(H)[N,DIN] @ W[DIN,DOUT] + b. 4 cols/thread, float4 loads.
template <int DIN, int DOUT, bool RELU>
__global__ void gemm4(const float* __restrict__ H, const float* __restrict__ W,
                      const float* __restrict__ b, float* __restrict__ out, int N) {
    __shared__ float Ws[DIN * DOUT];
    for (int i = threadIdx.x; i < DIN * DOUT / 4; i += blockDim.x)
        ((float4*)Ws)[i] = ((const float4*)W)[i];
    __syncthreads();

    int gid = blockIdx.x * blockDim.x + threadIdx.x;
    int row = gid / (DOUT / 4);
    int cg = (gid - row * (DOUT / 4)) * 4;
    if (row >= N) return;

    const float* h = H + (long)row * DIN;
    float4 acc = *(const float4*)&b[cg];
#pragma unroll
    for (int k0 = 0; k0 < DIN; k0 += 4) {
        float4 hv = *(const float4*)&h[k0];
        if (RELU) {
            hv.x = fmaxf(hv.x, 0.f); hv.y = fmaxf(hv.y, 0.f);
            hv.z = fmaxf(hv.z, 0.f); hv.w = fmaxf(hv.w, 0.f);
        }
#pragma unroll
        for (int kk = 0; kk < 4; ++kk) {
            float x = (&hv.x)[kk];
            float4 wv = *(const float4*)&Ws[(k0 + kk) * DOUT + cg];
            acc.x = fmaf(x, wv.x, acc.x); acc.y = fmaf(x, wv.y, acc.y);
            acc.z = fmaf(x, wv.z, acc.z); acc.w = fmaf(x, wv.w, acc.w);
        }
    }
    *(float4*)&out[(long)row * DOUT + cg] = acc;
}

// final projection 64->10, thread per output element
template <int DIN, int DOUT, bool RELU>
__global__ void gemm_simple(const float* __restrict__ H, const float* __restrict__ W,
                            const float* __restrict__ b, float* __restrict__ out, int N) {
    __shared__ float Ws[DIN * DOUT];
    for (int i = threadIdx.x; i < DIN * DOUT; i += blockDim.x) Ws[i] = W[i];
    __syncthreads();
    int gid = blockIdx.x * blockDim.x + threadIdx.x;
    int row = gid / DOUT;
    int col = gid - row * DOUT;
    if (row >= N) return;
    const float* h = H + (long)row * DIN;
    float acc = b[col];
#pragma unroll
    for (int k = 0; k < DIN; ++k) {
        float x = h[k];
        if (RELU) x = fmaxf(x, 0.f);
        acc = fmaf(x, Ws[k * DOUT + col], acc);
    }
    out[gid] = acc;
}

// ======================== CSR aggregation ==================================
// One wave per node, lane = feature. Zero atomics; each output row written once.
__global__ void agg64(const float* __restrict__ P, const int* __restrict__ row_ptr,
                      const int* __restrict__ csr_src, const float* __restrict__ csr_w,
                      float* __restrict__ A, int N) {
    int lane = threadIdx.x & 63;
    long gw = ((long)blockIdx.x * blockDim.x + threadIdx.x) >> 6;
    if (gw >= N) return;
    int n = (int)gw;
    int beg = row_ptr[n], end = row_ptr[n + 1];
    float acc = 0.f;
    int j = beg;
    for (; j + 1 < end; j += 2) {  // 2-deep for load ILP
        int s0 = csr_src[j], s1 = csr_src[j + 1];
        float w0 = csr_w[j], w1 = csr_w[j + 1];
        float v0 = P[(long)s0 * 64 + lane];
        float v1 = P[(long)s1 * 64 + lane];
        acc = fmaf(w0, v0, acc);
        acc = fmaf(w1, v1, acc);
    }
    if (j < end) {
        int s = csr_src[j];
        acc = fmaf(csr_w[j], P[(long)s * 64 + lane], acc);
    }
    A[(long)n * 64 + lane] = acc;
}

// final layer: wave per node, lanes 0..9 active
__global__ void agg10(const float* __restrict__ P, const int* __restrict__ row_ptr,
                      const int* __restrict__ csr_src, const float* __restrict__ csr_w,
                      float* __restrict__ out, int N) {
    int lane = threadIdx.x & 63;
    long gw = ((long)blockIdx.x * blockDim.x + threadIdx.x) >> 6;
    if (gw >= N) return;
    int n = (int)gw;
    int beg = row_ptr[n], end = row_ptr[n + 1];
    float acc = 0.f;
    for (int j = beg; j < end; ++j) {
        int s = csr_src[j];
        float w = csr_w[j];
        if (lane < 10) acc = fmaf(w, P[(long)s * 10 + lane], acc);
    }
    if (lane < 10) out[(long)n * 10 + lane] = acc;
}

// ============================ driver =======================================
extern "C" void kernel_launch(void* const* d_in, const int* in_sizes, int n_in,
                              void* d_out, int out_size, void* d_ws, size_t ws_size,
                              hipStream_t stream) {
    const float* x        = (const float*)d_in[0];
    const int*   edge_src = (const int*)d_in[1];
    const int*   edge_dst = (const int*)d_in[2];
    const float* edge_w   = (const float*)d_in[3];
    const float* W0 = (const float*)d_in[4];   const float* b0 = (const float*)d_in[5];
    const float* W1 = (const float*)d_in[6];   const float* b1 = (const float*)d_in[7];
    const float* W2 = (const float*)d_in[8];   const float* b2 = (const float*)d_in[9];
    const float* W3 = (const float*)d_in[10];  const float* b3 = (const float*)d_in[11];
    const float* W4 = (const float*)d_in[12];  const float* b4 = (const float*)d_in[13];
    float* out = (float*)d_out;

    // ---- workspace layout (all 256B-aligned) ----
    char* p = (char*)d_ws;
    auto take = [&](size_t bytes) { char* r = p; p += (bytes + 255) & ~(size_t)255; return r; };
    float* P        = (float*)take((size_t)N_NODES * 64 * sizeof(float));   // 25.6 MB
    float* A        = (float*)take((size_t)N_NODES * 64 * sizeof(float));   // 25.6 MB
    int*   csr_src  = (int*)  take((size_t)N_EDGES * sizeof(int));          // 6.4 MB
    float* csr_w    = (float*)take((size_t)N_EDGES * sizeof(float));        // 6.4 MB
    int*   deg      = (int*)  take((size_t)N_NODES * sizeof(int));
    int*   row_ptr  = (int*)  take((size_t)(N_NODES + 1) * sizeof(int));
    int*   cursor   = (int*)  take((size_t)N_NODES * sizeof(int));
    int*   partials = (int*)  take(1024 * sizeof(int));

    const int NB = (N_NODES + 1023) / 1024;          // 98 scan chunks
    const int EB = (N_EDGES + 255) / 256;            // edge-parallel blocks

    // ---- CSR build (amortized over 5 layers) ----
    hipMemsetAsync(deg, 0, (size_t)N_NODES * sizeof(int), stream);
    hist_kernel<<<EB, 256, 0, stream>>>(edge_dst, deg, N_EDGES);
    scan1<<<NB, 1024, 0, stream>>>(deg, row_ptr, partials, N_NODES);
    scan2<<<1, 128, 0, stream>>>(partials, NB);
    scan3<<<NB, 1024, 0, stream>>>(row_ptr, cursor, partials, N_NODES, N_EDGES);
    place_kernel<<<EB, 256, 0, stream>>>(edge_src, edge_dst, edge_w, cursor,
                                         csr_src, csr_w, N_EDGES);

    const int AGG_BLOCKS = (N_NODES * 64 + 255) / 256;  // one wave per node

    // ---- Layer 0: x @ W0 -> P ; aggregate -> A ----
    gemm4<128, 64, false><<<(N_NODES * 16 + 255) / 256, 256, 0, stream>>>(x, W0, b0, P, N_NODES);
    agg64<<<AGG_BLOCKS, 256, 0, stream>>>(P, row_ptr, csr_src, csr_w, A, N_NODES);

    // ---- Layers 1..3 ----
    const float* Ws_[3] = {W1, W2, W3};
    const float* bs_[3] = {b1, b2, b3};
    for (int l = 0; l < 3; ++l) {
        gemm4<64, 64, true><<<(N_NODES * 16 + 255) / 256, 256, 0, stream>>>(A, Ws_[l], bs_[l], P, N_NODES);
        agg64<<<AGG_BLOCKS, 256, 0, stream>>>(P, row_ptr, csr_src, csr_w, A, N_NODES);
    }

    // ---- Layer 4: relu(A) @ W4 -> P(10) ; aggregate -> out ----
    gemm_simple<64, 10, true><<<(N_NODES * 10 + 255) / 256, 256, 0, stream>>>(A, W4, b4, P, N_NODES);
    agg10<<<AGG_BLOCKS, 256, 0, stream>>>(P, row_ptr, csr_src, csr_w, out, N_NODES);
}